// Round 9
// baseline (67.017 us; speedup 1.0000x reference)
//
#include <hip/hip_runtime.h>
#include <hip/hip_bf16.h>

// Causal MHA forward: S=2048, H=16, D=128, fp32 in/out, bf16 MFMA internally.
// Prepass: K -> bf16 [h][s][d], V -> bf16 transposed [h][d][s] into d_ws.
// Main: 256 uniform blocks (h fastest), each runs tile qtA=31-j then qtB=j
// (33 chunks), 8 waves = 2qf x 4kh. Swapped QK^T leaves P in the exact
// B-operand layout of v_mfma_f32_16x16x16_bf16 -> PV = Vt*P (O^T) with P in
// registers: no P LDS round-trip, ONE barrier per chunk. 3-buffer KV pipeline,
// counted vmcnt(4), raw s_barrier. Fixed-bound softmax p=exp(s-14).
#define S_LEN 2048
#define NH 16
#define HD 128
#define KBLK 64
#define SM_BOUND 14.0f

typedef short short8 __attribute__((ext_vector_type(8)));
typedef short short4v __attribute__((ext_vector_type(4)));
typedef float f32x4 __attribute__((ext_vector_type(4)));

#if __has_builtin(__builtin_amdgcn_mfma_f32_16x16x16bf16_1k)
#define HAVE_MFMA16 1
#define MFMA16(a, b, c) __builtin_amdgcn_mfma_f32_16x16x16bf16_1k(a, b, c, 0, 0, 0)
#else
#define HAVE_MFMA16 0
#endif

__device__ __forceinline__ ushort f2bf(float f) {
  union { float f; unsigned u; } v; v.f = f;
  unsigned u = v.u;
  return (ushort)((u + 0x7fffu + ((u >> 16) & 1u)) >> 16);  // RNE
}

// global (AS1) -> LDS (AS3) direct 16B load; source pre-swizzled, dest linear.
#define GLDS(gp, lp)                                                      \
  __builtin_amdgcn_global_load_lds(                                       \
      (const __attribute__((address_space(1))) void*)(gp),                \
      (__attribute__((address_space(3))) void*)(lp), 16, 0, 0)

// ---------------- prepass: convert + transpose (proven r2-r8) ----------------
__global__ __launch_bounds__(256)
void prep(const float* __restrict__ Kg, const float* __restrict__ Vg,
          ushort* __restrict__ Kb, ushort* __restrict__ Vb) {
  __shared__ ushort lt[64 * HD];  // 16 KB, swizzled
  const int tid = threadIdx.x;
  const int h = blockIdx.x & 15;
  const int j0 = (blockIdx.x >> 4) * 64;

#pragma unroll
  for (int it = 0; it < 8; ++it) {
    int flat = it * 256 + tid;       // float4 index over 64x32
    int r = flat >> 5, d4 = (flat & 31) * 4;
    float4 v = *(const float4*)(Kg + ((size_t)(j0 + r) * NH + h) * HD + d4);
    ushort4 b;
    b.x = f2bf(v.x); b.y = f2bf(v.y); b.z = f2bf(v.z); b.w = f2bf(v.w);
    *(ushort4*)(Kb + ((size_t)h * S_LEN + j0 + r) * HD + d4) = b;
  }
#pragma unroll
  for (int it = 0; it < 8; ++it) {
    int flat = it * 256 + tid;
    int r = flat >> 5, d4 = (flat & 31) * 4;
    float4 v = *(const float4*)(Vg + ((size_t)(j0 + r) * NH + h) * HD + d4);
    ushort4 b;
    b.x = f2bf(v.x); b.y = f2bf(v.y); b.z = f2bf(v.z); b.w = f2bf(v.w);
    *(ushort4*)(&lt[r * 128 + (d4 ^ ((r & 7) << 3))]) = b;
  }
  __syncthreads();
  const int d = tid >> 1, half = tid & 1;
  ushort vals[32];
#pragma unroll
  for (int j = 0; j < 32; ++j) {
    int jjj = half * 32 + j;
    vals[j] = lt[jjj * 128 + (d ^ ((jjj & 7) << 3))];
  }
  ushort* dst = Vb + ((size_t)h * HD + d) * S_LEN + j0 + half * 32;
#pragma unroll
  for (int q = 0; q < 4; ++q) {
    short8 w;
#pragma unroll
    for (int e = 0; e < 8; ++e) w[e] = (short)vals[q * 8 + e];
    *(short8*)(dst + q * 8) = w;
  }
}

#if HAVE_MFMA16
// ---------------- main (K=16 PV, P in registers, O^T accumulate) ----------------
__global__ __launch_bounds__(512, 2)
void attn_main(const float* __restrict__ Qg, const ushort* __restrict__ Kb,
               const ushort* __restrict__ Vb, float* __restrict__ Og) {
  __shared__ ushort lds_k[3][KBLK * HD];    // 3 x 16 KB, [64 k][128 d] swizzled
  __shared__ ushort lds_vt[3][HD * KBLK];   // 3 x 16 KB, [128 d][64 k] swizzled
  __shared__ float  osc[2][4096];           // 32 KB epilogue O^T combine
  __shared__ float  lsc[2][4][2][16];       // 1 KB l partials [qf][kh][qc][lr]

  const int tid = threadIdx.x;
  const int l   = tid & 63;
  const int wv  = tid >> 6;      // 0..7
  const int qf  = wv >> 2;       // 0..1: 32-q group
  const int kh  = wv & 3;        // 0..3: 16-k quarter
  const int lr  = l & 15;
  const int lg  = l >> 4;

  const int bid = blockIdx.x;
  const int h   = bid & 15;
  const int jj  = bid >> 4;      // 0..15
  const int qtA = 31 - jj;       // 16..31
  const int qbA = qtA * 64, qbB = jj * 64;

  const ushort* khp = Kb + (size_t)h * S_LEN * HD;
  const ushort* vhp = Vb + (size_t)h * HD * S_LEN;

  // staging offsets (pre-swizzled global source, linear LDS dest; rule #21)
  const int b0 = tid, b1 = 512 + tid;
  const int r0 = b0 >> 4, r1 = b1 >> 4;
  const int koff0 = r0 * 128 + (((b0 & 15) ^ (r0 & 7)) << 3);
  const int koff1 = r1 * 128 + (((b1 & 15) ^ (r1 & 7)) << 3);
  const int dd0 = b0 >> 3, dd1 = b1 >> 3;
  const int voff0 = dd0 * S_LEN + (((b0 & 7) ^ (dd0 & 7)) << 3);
  const int voff1 = dd1 * S_LEN + (((b1 & 7) ^ (dd1 & 7)) << 3);

  auto stage = [&](int buf, int kc) {
    const ushort* kbase = khp + (size_t)kc * (KBLK * HD);
    GLDS(kbase + koff0, &lds_k[buf][tid * 8]);
    GLDS(kbase + koff1, &lds_k[buf][4096 + tid * 8]);
    const ushort* vbase = vhp + (size_t)kc * KBLK;
    GLDS(vbase + voff0, &lds_vt[buf][tid * 8]);
    GLDS(vbase + voff1, &lds_vt[buf][4096 + tid * 8]);
  };

  // Q preload for BOTH tiles (B-operand layout), scale folded in.
  const float scale = 0.08838834764831845f;  // 1/sqrt(128)
  short8 qfrA[2][4], qfrB[2][4];
  auto loadQ = [&](short8 (&dst)[2][4], int qb) {
#pragma unroll
    for (int qc = 0; qc < 2; ++qc) {
      const float* qsrc = Qg + ((size_t)(qb + qf * 32 + qc * 16 + lr) * NH + h) * HD;
#pragma unroll
      for (int dk = 0; dk < 4; ++dk) {
        float4 a = *(const float4*)(qsrc + dk * 32 + lg * 8);
        float4 b2 = *(const float4*)(qsrc + dk * 32 + lg * 8 + 4);
        short8 f;
        f[0] = (short)f2bf(a.x * scale);  f[1] = (short)f2bf(a.y * scale);
        f[2] = (short)f2bf(a.z * scale);  f[3] = (short)f2bf(a.w * scale);
        f[4] = (short)f2bf(b2.x * scale); f[5] = (short)f2bf(b2.y * scale);
        f[6] = (short)f2bf(b2.z * scale); f[7] = (short)f2bf(b2.w * scale);
        dst[qc][dk] = f;
      }
    }
  };
  loadQ(qfrA, qbA);
  loadQ(qfrB, qbB);

  // O^T partial: oaccT[qc][dt]; q = qf*32+qc*16+lr (col), d = dt*16+lg*4+i (row)
  f32x4 oaccT[2][8];
#pragma unroll
  for (int qc = 0; qc < 2; ++qc)
#pragma unroll
    for (int dt = 0; dt < 8; ++dt) oaccT[qc][dt] = (f32x4){0.f, 0.f, 0.f, 0.f};
  float l_run[2] = {0.f, 0.f};

  // epilogue: 4-way kh combine of O^T via osc, l via lsc; kh==3 finalizes.
  auto epilogue = [&](int qb) {
    float t0 = l_run[0], t1 = l_run[1];
    t0 += __shfl_xor(t0, 16, 64); t0 += __shfl_xor(t0, 32, 64);
    t1 += __shfl_xor(t1, 16, 64); t1 += __shfl_xor(t1, 32, 64);
    if (lg == 0) { lsc[qf][kh][0][lr] = t0; lsc[qf][kh][1][lr] = t1; }
    if (kh == 0) {
#pragma unroll
      for (int qc = 0; qc < 2; ++qc)
#pragma unroll
        for (int dt = 0; dt < 8; ++dt) {
          int q = qc * 16 + lr;
          int du = (((dt * 4 + lg) ^ (q & 7)) << 2);
          *(f32x4*)&osc[qf][q * 128 + du] = oaccT[qc][dt];
        }
    }
    __syncthreads();
    if (kh == 1) {
#pragma unroll
      for (int qc = 0; qc < 2; ++qc)
#pragma unroll
        for (int dt = 0; dt < 8; ++dt) {
          int q = qc * 16 + lr;
          int du = (((dt * 4 + lg) ^ (q & 7)) << 2);
          f32x4 v = *(const f32x4*)&osc[qf][q * 128 + du];
          v += oaccT[qc][dt];
          *(f32x4*)&osc[qf][q * 128 + du] = v;
        }
    }
    __syncthreads();
    if (kh == 2) {
#pragma unroll
      for (int qc = 0; qc < 2; ++qc)
#pragma unroll
        for (int dt = 0; dt < 8; ++dt) {
          int q = qc * 16 + lr;
          int du = (((dt * 4 + lg) ^ (q & 7)) << 2);
          f32x4 v = *(const f32x4*)&osc[qf][q * 128 + du];
          v += oaccT[qc][dt];
          *(f32x4*)&osc[qf][q * 128 + du] = v;
        }
    }
    __syncthreads();
    if (kh == 3) {
      float inv[2];
#pragma unroll
      for (int qc = 0; qc < 2; ++qc)
        inv[qc] = 1.0f / ((lsc[qf][0][qc][lr] + lsc[qf][1][qc][lr]) +
                          (lsc[qf][2][qc][lr] + lsc[qf][3][qc][lr]));
#pragma unroll
      for (int qc = 0; qc < 2; ++qc)
#pragma unroll
        for (int dt = 0; dt < 8; ++dt) {
          int q = qc * 16 + lr;
          int du = (((dt * 4 + lg) ^ (q & 7)) << 2);
          f32x4 v = *(const f32x4*)&osc[qf][q * 128 + du];
          v += oaccT[qc][dt];
          int qg = qb + qf * 32 + q;
          float4 o;
          o.x = v[0] * inv[qc]; o.y = v[1] * inv[qc];
          o.z = v[2] * inv[qc]; o.w = v[3] * inv[qc];
          *(float4*)(Og + ((size_t)qg * NH + h) * HD + dt * 16 + lg * 4) = o;
        }
    }
  };

  stage(0, 0);
  stage(1, 1);  // qtA >= 16, so chunk 1 is always tile A

  for (int g = 0; g < 33; ++g) {
    // top barrier: own chunk-g loads landed (counted), block-wide sync.
    if (g == 32) { asm volatile("s_waitcnt vmcnt(0)" ::: "memory"); }
    else         { asm volatile("s_waitcnt vmcnt(4)" ::: "memory"); }
    asm volatile("s_barrier" ::: "memory");
    if (g + 2 < 33) {
      int t = g + 2;
      stage(t % 3, (t <= qtA) ? t : (t - qtA - 1));  // prefetch flies across barriers
    }
    const int bI = g % 3;
    const ushort* lk = lds_k[bI];
    const ushort* lv = lds_vt[bI];
    const bool tB = (g > qtA);
    const int kc = tB ? (g - qtA - 1) : g;
    const int qb = tB ? qbB : qbA;

    // ---- QK^T: A=K rows (kh 16k), B=Q (2 qc); C: lane = (k=lg*4+i, q=lr) ----
    f32x4 s0 = (f32x4){0.f, 0.f, 0.f, 0.f};
    f32x4 s1 = (f32x4){0.f, 0.f, 0.f, 0.f};
    const int krow = kh * 16 + lr;
    __builtin_amdgcn_s_setprio(1);
    if (!tB) {
#pragma unroll
      for (int dk = 0; dk < 4; ++dk) {
        short8 kf = *(const short8*)&lk[krow * 128 + ((dk * 32 + lg * 8) ^ ((lr & 7) << 3))];
        s0 = __builtin_amdgcn_mfma_f32_16x16x32_bf16(kf, qfrA[0][dk], s0, 0, 0, 0);
        s1 = __builtin_amdgcn_mfma_f32_16x16x32_bf16(kf, qfrA[1][dk], s1, 0, 0, 0);
      }
    } else {
#pragma unroll
      for (int dk = 0; dk < 4; ++dk) {
        short8 kf = *(const short8*)&lk[krow * 128 + ((dk * 32 + lg * 8) ^ ((lr & 7) << 3))];
        s0 = __builtin_amdgcn_mfma_f32_16x16x32_bf16(kf, qfrB[0][dk], s0, 0, 0, 0);
        s1 = __builtin_amdgcn_mfma_f32_16x16x32_bf16(kf, qfrB[1][dk], s1, 0, 0, 0);
      }
    }
    __builtin_amdgcn_s_setprio(0);

    // ---- fixed-bound softmax; mask only on diagonal chunks ----
    float p0[4], p1[4];
    if (g == qtA || g == 32) {
      const int qg0 = qb + qf * 32 + lr;
#pragma unroll
      for (int i = 0; i < 4; ++i) {
        int kg = kc * 64 + kh * 16 + lg * 4 + i;
        float e0 = __expf(s0[i] - SM_BOUND);
        float e1 = __expf(s1[i] - SM_BOUND);
        p0[i] = (kg > qg0) ? 0.f : e0;
        p1[i] = (kg > qg0 + 16) ? 0.f : e1;
      }
    } else {
#pragma unroll
      for (int i = 0; i < 4; ++i) {
        p0[i] = __expf(s0[i] - SM_BOUND);
        p1[i] = __expf(s1[i] - SM_BOUND);
      }
    }
    l_run[0] += (p0[0] + p0[1]) + (p0[2] + p0[3]);
    l_run[1] += (p1[0] + p1[1]) + (p1[2] + p1[3]);

    // ---- P (C-layout) == B-operand of K=16 MFMA: pack to bf16 in-register ----
    short4v pb0, pb1;
    {
      union { unsigned u[2]; short4v v; } c0, c1;
      asm("v_cvt_pk_bf16_f32 %0, %1, %2" : "=v"(c0.u[0]) : "v"(p0[0]), "v"(p0[1]));
      asm("v_cvt_pk_bf16_f32 %0, %1, %2" : "=v"(c0.u[1]) : "v"(p0[2]), "v"(p0[3]));
      asm("v_cvt_pk_bf16_f32 %0, %1, %2" : "=v"(c1.u[0]) : "v"(p1[0]), "v"(p1[1]));
      asm("v_cvt_pk_bf16_f32 %0, %1, %2" : "=v"(c1.u[1]) : "v"(p1[2]), "v"(p1[3]));
      pb0 = c0.v; pb1 = c1.v;
    }

    // ---- PV (O^T): A=Vt[d=dt*16+lr][k=kh*16+lg*4..+3], B=P; K=16 MFMA ----
    __builtin_amdgcn_s_setprio(1);
#pragma unroll
    for (int dt = 0; dt < 8; ++dt) {
      int d = dt * 16 + lr;
      short4v va = *(const short4v*)&lv[d * 64 + ((kh * 16 + lg * 4) ^ ((d & 7) << 3))];
      oaccT[0][dt] = MFMA16(va, pb0, oaccT[0][dt]);
      oaccT[1][dt] = MFMA16(va, pb1, oaccT[1][dt]);
    }
    __builtin_amdgcn_s_setprio(0);

    if (g == qtA) {   // tile A done: combine + write, reset for tile B
      epilogue(qbA);
#pragma unroll
      for (int qc = 0; qc < 2; ++qc)
#pragma unroll
        for (int dt = 0; dt < 8; ++dt) oaccT[qc][dt] = (f32x4){0.f, 0.f, 0.f, 0.f};
      l_run[0] = 0.f; l_run[1] = 0.f;
    }
  }
  epilogue(qbB);
}

#else  // !HAVE_MFMA16 -- round-8 proven body (K=32 PV via LDS-P)

__global__ __launch_bounds__(512, 2)
void attn_main(const float* __restrict__ Qg, const ushort* __restrict__ Kb,
               const ushort* __restrict__ Vb, float* __restrict__ Og) {
  __shared__ ushort lds_k[3][KBLK * HD];
  __shared__ ushort lds_vt[3][HD * KBLK];
  __shared__ ushort lds_p[64 * 64];
  __shared__ float  lsc[2][4][2][16];

  const int tid = threadIdx.x;
  const int l   = tid & 63;
  const int wv  = tid >> 6;
  const int qf  = wv >> 2;
  const int kh  = wv & 3;
  const int dh  = wv & 3;
  const int lr  = l & 15;
  const int lg  = l >> 4;

  const int bid = blockIdx.x;
  const int h   = bid & 15;
  const int jj  = bid >> 4;
  const int qtA = 31 - jj;
  const int qbA = qtA * 64, qbB = jj * 64;

  const ushort* khp = Kb + (size_t)h * S_LEN * HD;
  const ushort* vhp = Vb + (size_t)h * HD * S_LEN;

  const int b0 = tid, b1 = 512 + tid;
  const int r0 = b0 >> 4, r1 = b1 >> 4;
  const int koff0 = r0 * 128 + (((b0 & 15) ^ (r0 & 7)) << 3);
  const int koff1 = r1 * 128 + (((b1 & 15) ^ (r1 & 7)) << 3);
  const int dd0 = b0 >> 3, dd1 = b1 >> 3;
  const int voff0 = dd0 * S_LEN + (((b0 & 7) ^ (dd0 & 7)) << 3);
  const int voff1 = dd1 * S_LEN + (((b1 & 7) ^ (dd1 & 7)) << 3);

  auto stage = [&](int buf, int kc) {
    const ushort* kbase = khp + (size_t)kc * (KBLK * HD);
    GLDS(kbase + koff0, &lds_k[buf][tid * 8]);
    GLDS(kbase + koff1, &lds_k[buf][4096 + tid * 8]);
    const ushort* vbase = vhp + (size_t)kc * KBLK;
    GLDS(vbase + voff0, &lds_vt[buf][tid * 8]);
    GLDS(vbase + voff1, &lds_vt[buf][4096 + tid * 8]);
  };

  const float scale = 0.08838834764831845f;
  short8 qfrA[2][4], qfrB[2][4];
  auto loadQ = [&](short8 (&dst)[2][4], int qb) {
#pragma unroll
    for (int qc = 0; qc < 2; ++qc) {
      const float* qsrc = Qg + ((size_t)(qb + qf * 32 + qc * 16 + lr) * NH + h) * HD;
#pragma unroll
      for (int dk = 0; dk < 4; ++dk) {
        float4 a = *(const float4*)(qsrc + dk * 32 + lg * 8);
        float4 b2 = *(const float4*)(qsrc + dk * 32 + lg * 8 + 4);
        short8 f;
        f[0] = (short)f2bf(a.x * scale);  f[1] = (short)f2bf(a.y * scale);
        f[2] = (short)f2bf(a.z * scale);  f[3] = (short)f2bf(a.w * scale);
        f[4] = (short)f2bf(b2.x * scale); f[5] = (short)f2bf(b2.y * scale);
        f[6] = (short)f2bf(b2.z * scale); f[7] = (short)f2bf(b2.w * scale);
        dst[qc][dk] = f;
      }
    }
  };
  loadQ(qfrA, qbA);
  loadQ(qfrB, qbB);

  f32x4 oacc[2][2];
#pragma unroll
  for (int qc = 0; qc < 2; ++qc)
#pragma unroll
    for (int dt = 0; dt < 2; ++dt) oacc[qc][dt] = (f32x4){0.f, 0.f, 0.f, 0.f};
  float l_run[2] = {0.f, 0.f};

  auto epilogue = [&](int qb) {
    float t0 = l_run[0], t1 = l_run[1];
    t0 += __shfl_xor(t0, 16, 64); t0 += __shfl_xor(t0, 32, 64);
    t1 += __shfl_xor(t1, 16, 64); t1 += __shfl_xor(t1, 32, 64);
    if (lg == 0) { lsc[qf][kh][0][lr] = t0; lsc[qf][kh][1][lr] = t1; }
    __syncthreads();
    float inv[2][4];
#pragma unroll
    for (int qc = 0; qc < 2; ++qc)
#pragma unroll
      for (int i = 0; i < 4; ++i) {
        int q15 = lg * 4 + i;
        float sl = (lsc[qf][0][qc][q15] + lsc[qf][1][qc][q15]) +
                   (lsc[qf][2][qc][q15] + lsc[qf][3][qc][q15]);
        inv[qc][i] = 1.0f / sl;
      }
#pragma unroll
    for (int qc = 0; qc < 2; ++qc)
#pragma unroll
      for (int dt = 0; dt < 2; ++dt)
#pragma unroll
        for (int i = 0; i < 4; ++i) {
          int qg = qb + qf * 32 + qc * 16 + lg * 4 + i;
          Og[((size_t)qg * NH + h) * HD + dh * 32 + dt * 16 + lr] =
              oacc[qc][dt][i] * inv[qc][i];
        }
  };

  stage(0, 0);
  stage(1, 1);

  for (int g = 0; g < 33; ++g) {
    if (g == 32) { asm volatile("s_waitcnt vmcnt(0)" ::: "memory"); }
    else         { asm volatile("s_waitcnt vmcnt(4)" ::: "memory"); }
    asm volatile("s_barrier" ::: "memory");
    if (g + 2 < 33) {
      int t = g + 2;
      stage(t % 3, (t <= qtA) ? t : (t - qtA - 1));
    }
    const int bI = g % 3;
    const ushort* lk = lds_k[bI];
    const ushort* lv = lds_vt[bI];
    const bool tB = (g > qtA);
    const int kc = tB ? (g - qtA - 1) : g;
    const int qb = tB ? qbB : qbA;

    f32x4 s0 = (f32x4){0.f, 0.f, 0.f, 0.f};
    f32x4 s1 = (f32x4){0.f, 0.f, 0.f, 0.f};
    const int krow = kh * 16 + lr;
    __builtin_amdgcn_s_setprio(1);
    if (!tB) {
#pragma unroll
      for (int dk = 0; dk < 4; ++dk) {
        short8 kf = *(const short8*)&lk[krow * 128 + ((dk * 32 + lg * 8) ^ ((lr & 7) << 3))];
        s0 = __builtin_amdgcn_mfma_f32_16x16x32_bf16(kf, qfrA[0][dk], s0, 0, 0, 0);
        s1 = __builtin_amdgcn_mfma_f32_16x16x32_bf16(kf, qfrA[1][dk], s1, 0, 0, 0);
      }
    } else {
#pragma unroll
      for (int dk = 0; dk < 4; ++dk) {
        short8 kf = *(const short8*)&lk[krow * 128 + ((dk * 32 + lg * 8) ^ ((lr & 7) << 3))];
        s0 = __builtin_amdgcn_mfma_f32_16x16x32_bf16(kf, qfrB[0][dk], s0, 0, 0, 0);
        s1 = __builtin_amdgcn_mfma_f32_16x16x32_bf16(kf, qfrB[1][dk], s1, 0, 0, 0);
      }
    }
    __builtin_amdgcn_s_setprio(0);

    float p0[4], p1[4];
    if (g == qtA || g == 32) {
      const int qg0 = qb + qf * 32 + lr;
#pragma unroll
      for (int i = 0; i < 4; ++i) {
        int kg = kc * 64 + kh * 16 + lg * 4 + i;
        float e0 = __expf(s0[i] - SM_BOUND);
        float e1 = __expf(s1[i] - SM_BOUND);
        p0[i] = (kg > qg0) ? 0.f : e0;
        p1[i] = (kg > qg0 + 16) ? 0.f : e1;
      }
    } else {
#pragma unroll
      for (int i = 0; i < 4; ++i) {
        p0[i] = __expf(s0[i] - SM_BOUND);
        p1[i] = __expf(s1[i] - SM_BOUND);
      }
    }
    l_run[0] += (p0[0] + p0[1]) + (p0[2] + p0[3]);
    l_run[1] += (p1[0] + p1[1]) + (p1[2] + p1[3]);

    {
      int q0 = qf * 32 + lr;
      int q1 = q0 + 16;
      unsigned w;
      asm("v_cvt_pk_bf16_f32 %0, %1, %2" : "=v"(w) : "v"(p0[0]), "v"(p0[1]));
      *(unsigned*)&lds_p[q0 * 64 + ((kh * 16 + lg * 4 + 0) ^ ((q0 & 7) << 3))] = w;
      asm("v_cvt_pk_bf16_f32 %0, %1, %2" : "=v"(w) : "v"(p0[2]), "v"(p0[3]));
      *(unsigned*)&lds_p[q0 * 64 + ((kh * 16 + lg * 4 + 2) ^ ((q0 & 7) << 3))] = w;
      asm("v_cvt_pk_bf16_f32 %0, %1, %2" : "=v"(w) : "v"(p1[0]), "v"(p1[1]));
      *(unsigned*)&lds_p[q1 * 64 + ((kh * 16 + lg * 4 + 0) ^ ((q1 & 7) << 3))] = w;
      asm("v_cvt_pk_bf16_f32 %0, %1, %2" : "=v"(w) : "v"(p1[2]), "v"(p1[3]));
      *(unsigned*)&lds_p[q1 * 64 + ((kh * 16 + lg * 4 + 2) ^ ((q1 & 7) << 3))] = w;
    }
    asm volatile("s_waitcnt lgkmcnt(0)" ::: "memory");
    asm volatile("s_barrier" ::: "memory");
    __builtin_amdgcn_sched_barrier(0);

    short8 pa0[2], pa1[2];
    {
      int q0 = qf * 32 + lr;
      int q1 = q0 + 16;
      pa0[0] = *(const short8*)&lds_p[q0 * 64 + ((lg * 8) ^ ((q0 & 7) << 3))];
      pa0[1] = *(const short8*)&lds_p[q0 * 64 + ((32 + lg * 8) ^ ((q0 & 7) << 3))];
      pa1[0] = *(const short8*)&lds_p[q1 * 64 + ((lg * 8) ^ ((q1 & 7) << 3))];
      pa1[1] = *(const short8*)&lds_p[q1 * 64 + ((32 + lg * 8) ^ ((q1 & 7) << 3))];
    }
    __builtin_amdgcn_s_setprio(1);
#pragma unroll
    for (int dt = 0; dt < 2; ++dt) {
      int d = dh * 32 + dt * 16 + lr;
#pragma unroll
      for (int ks = 0; ks < 2; ++ks) {
        short8 vf = *(const short8*)&lv[d * 64 + ((ks * 32 + lg * 8) ^ ((d & 7) << 3))];
        oacc[0][dt] = __builtin_amdgcn_mfma_f32_16x16x32_bf16(pa0[ks], vf, oacc[0][dt], 0, 0, 0);
        oacc[1][dt] = __builtin_amdgcn_mfma_f32_16x16x32_bf16(pa1[ks], vf, oacc[1][dt], 0, 0, 0);
      }
    }
    __builtin_amdgcn_s_setprio(0);

    if (g == qtA) {
      epilogue(qbA);
#pragma unroll
      for (int qc = 0; qc < 2; ++qc)
#pragma unroll
        for (int dt = 0; dt < 2; ++dt) oacc[qc][dt] = (f32x4){0.f, 0.f, 0.f, 0.f};
      l_run[0] = 0.f; l_run[1] = 0.f;
    }
  }
  epilogue(qbB);
}
#endif  // HAVE_MFMA16

// ---------------- fallback (no-ws, round-2 style, fixed-bound) ----------------
__global__ __launch_bounds__(256, 2)
void attn_fwd_fb(const float* __restrict__ Qg, const float* __restrict__ Kg,
                 const float* __restrict__ Vg, float* __restrict__ Og) {
  __shared__ ushort lds_k[KBLK * HD];
  __shared__ ushort lds_vt[HD * KBLK];
  __shared__ ushort lds_p[4][16 * KBLK];

  const int tid = threadIdx.x;
  const int l  = tid & 63;
  const int wv = tid >> 6;
  const int lr = l & 15;
  const int lg = l >> 4;

  const int bid = blockIdx.x;
  const int h  = bid & 15;
  const int qi = bid >> 4;
  const int qt = (qi < 16) ? (31 - 2 * qi) : (2 * (qi - 16));
  const int qbase = qt * 64;

  short8 qf[4];
  {
    const float* qsrc = Qg + ((size_t)(qbase + wv * 16 + lr) * NH + h) * HD;
#pragma unroll
    for (int dk = 0; dk < 4; ++dk) {
      float4 a = *(const float4*)(qsrc + dk * 32 + lg * 8);
      float4 b = *(const float4*)(qsrc + dk * 32 + lg * 8 + 4);
      short8 f;
      f[0] = (short)f2bf(a.x); f[1] = (short)f2bf(a.y);
      f[2] = (short)f2bf(a.z); f[3] = (short)f2bf(a.w);
      f[4] = (short)f2bf(b.x); f[5] = (short)f2bf(b.y);
      f[6] = (short)f2bf(b.z); f[7] = (short)f2bf(b.w);
      qf[dk] = f;
    }
  }

  f32x4 oacc[8];
#pragma unroll
  for (int dt = 0; dt < 8; ++dt) oacc[dt] = (f32x4){0.f, 0.f, 0.f, 0.f};
  float l_run[4] = {0.f, 0.f, 0.f, 0.f};

  const float scale = 0.08838834764831845f;
  const int nch = qt + 1;

  for (int c = 0; c < nch; ++c) {
    const int k0 = c * KBLK;
    __syncthreads();
#pragma unroll
    for (int it = 0; it < 8; ++it) {
      int flat = (it * 256 + tid) * 4;
      int r = flat >> 7, d = flat & 127;
      float4 v = *(const float4*)(Kg + ((size_t)(k0 + r) * NH + h) * HD + d);
      int idx = (r * 128 + d) ^ ((r & 7) << 3);
      ushort4 b4;
      b4.x = f2bf(v.x); b4.y = f2bf(v.y); b4.z = f2bf(v.z); b4.w = f2bf(v.w);
      *(ushort4*)&lds_k[idx] = b4;
    }
#pragma unroll
    for (int it = 0; it < 8; ++it) {
      int d0 = wv * 32 + it * 4;
      float4 v = *(const float4*)(Vg + ((size_t)(k0 + l) * NH + h) * HD + d0);
      lds_vt[((d0 + 0) * 64 + l) ^ (((d0 + 0) & 7) << 3)] = f2bf(v.x);
      lds_vt[((d0 + 1) * 64 + l) ^ (((d0 + 1) & 7) << 3)] = f2bf(v.y);
      lds_vt[((d0 + 2) * 64 + l) ^ (((d0 + 2) & 7) << 3)] = f2bf(v.z);
      lds_vt[((d0 + 3) * 64 + l) ^ (((d0 + 3) & 7) << 3)] = f2bf(v.w);
    }
    __syncthreads();

    f32x4 sacc[4];
#pragma unroll
    for (int kc = 0; kc < 4; ++kc) {
      sacc[kc] = (f32x4){0.f, 0.f, 0.f, 0.f};
#pragma unroll
      for (int dk = 0; dk < 4; ++dk) {
        int row = kc * 16 + lr;
        int idx = (row * 128 + dk * 32 + lg * 8) ^ ((row & 7) << 3);
        short8 kf = *(const short8*)&lds_k[idx];
        sacc[kc] = __builtin_amdgcn_mfma_f32_16x16x32_bf16(qf[dk], kf, sacc[kc], 0, 0, 0);
      }
    }

    float p[4][4];
    if (c == qt) {
#pragma unroll
      for (int i = 0; i < 4; ++i) {
        int qg = qbase + wv * 16 + lg * 4 + i;
#pragma unroll
        for (int kc = 0; kc < 4; ++kc) {
          float e = __expf(sacc[kc][i] * scale - SM_BOUND);
          p[kc][i] = (k0 + kc * 16 + lr > qg) ? 0.f : e;
        }
      }
    } else {
#pragma unroll
      for (int i = 0; i < 4; ++i)
#pragma unroll
        for (int kc = 0; kc < 4; ++kc)
          p[kc][i] = __expf(sacc[kc][i] * scale - SM_BOUND);
    }
#pragma unroll
    for (int i = 0; i < 4; ++i)
      l_run[i] += (p[0][i] + p[1][i]) + (p[2][i] + p[3][i]);

#pragma unroll
    for (int kc = 0; kc < 4; ++kc)
#pragma unroll
      for (int i = 0; i < 4; ++i) {
        int row = lg * 4 + i, col = kc * 16 + lr;
        lds_p[wv][(row * 64 + col) ^ ((row & 7) << 3)] = f2bf(p[kc][i]);
      }
    asm volatile("s_waitcnt lgkmcnt(0)" ::: "memory");
    __builtin_amdgcn_sched_barrier(0);

    short8 pa[2];
#pragma unroll
    for (int ks = 0; ks < 2; ++ks) {
      int idx = (lr * 64 + ks * 32 + lg * 8) ^ ((lr & 7) << 3);
      pa[ks] = *(const short8*)&lds_p[wv][idx];
    }

#pragma unroll
    for (int dt = 0; dt < 8; ++dt) {
#pragma unroll
      for (int ks = 0; ks < 2; ++ks) {
        int d = dt * 16 + lr;
        int idx = (d * 64 + ks * 32 + lg * 8) ^ ((d & 7) << 3);
        short8 vf = *(const short8*)&lds_vt[idx];
        oacc[dt] = __builtin_amdgcn_mfma_f32_16x16x32_bf16(pa[ks], vf, oacc[dt], 0, 0, 0);
      }
    }
  }

#pragma unroll
  for (int mk = 1; mk <= 8; mk <<= 1)
#pragma unroll
    for (int i = 0; i < 4; ++i)
      l_run[i] += __shfl_xor(l_run[i], mk, 64);
  float inv[4];
#pragma unroll
  for (int i = 0; i < 4; ++i) inv[i] = 1.0f / l_run[i];
#pragma unroll
  for (int dt = 0; dt < 8; ++dt)
#pragma unroll
    for (int i = 0; i < 4; ++i) {
      int qg = qbase + wv * 16 + lg * 4 + i;
      Og[((size_t)qg * NH + h) * HD + dt * 16 + lr] = oacc[dt][i] * inv[i];
    }
}

extern "C" void kernel_launch(void* const* d_in, const int* in_sizes, int n_in,
                              void* d_out, int out_size, void* d_ws, size_t ws_size,
                              hipStream_t stream) {
  (void)in_sizes; (void)n_in; (void)out_size;
  const float* Q = (const float*)d_in[0];
  const float* K = (const float*)d_in[1];
  const float* V = (const float*)d_in[2];
  float* O = (float*)d_out;

  const size_t elems = (size_t)S_LEN * NH * HD;        // 4M
  const size_t need = 2 * elems * sizeof(ushort);      // 16 MB
  if (ws_size >= need) {
    ushort* Kb = (ushort*)d_ws;
    ushort* Vb = Kb + elems;
    prep<<<dim3(512), dim3(256), 0, stream>>>(K, V, Kb, Vb);
    attn_main<<<dim3(256), dim3(512), 0, stream>>>(Q, Kb, Vb, O);
  } else {
    attn_fwd_fb<<<dim3(512), dim3(256), 0, stream>>>(Q, K, V, O);
  }
}